// Round 5
// baseline (195.341 us; speedup 1.0000x reference)
//
#include <hip/hip_runtime.h>
#include <hip/hip_bf16.h>
#include <math.h>

#define T_DIM 8192
#define D_DIM 128

typedef __attribute__((ext_vector_type(8))) __bf16 bf16x8;
typedef __attribute__((ext_vector_type(16))) float f32x16;
typedef __attribute__((ext_vector_type(4))) float f32x4;

static __device__ __forceinline__ unsigned short f2bf(float f) {
    unsigned u = __builtin_bit_cast(unsigned, f);
    unsigned r = (u + 0x7FFFu + ((u >> 16) & 1u)) >> 16;
    return (unsigned short)r;
}
static __device__ __forceinline__ float bf2f(unsigned short h) {
    unsigned u = ((unsigned)h) << 16;
    return __builtin_bit_cast(float, u);
}
static __device__ __forceinline__ float exp2_fast(float x) {
    float r;
    asm("v_exp_f32 %0, %1" : "=v"(r) : "v"(x));
    return r;
}

static __device__ __forceinline__ float gelu_tanh(float x) {
    const float c = 0.7978845608028654f; // sqrt(2/pi)
    float u = c * (x + 0.044715f * x * x * x);
    float e = __expf(2.0f * u);
    float th = 1.0f - 2.0f / (e + 1.0f);
    return 0.5f * x * (1.0f + th);
}
static __device__ __forceinline__ float softplus_f(float x) {
    return (x > 20.0f) ? x : log1pf(__expf(x));
}

// ---------------------------------------------------------------------------
// prep: gelu, row-normalize -> on (row-major bf16); raw gelu -> vT' transposed
// with per-32-block column permutation sigma(k) = swap bits 2<->3 (involution).
// ---------------------------------------------------------------------------
__global__ __launch_bounds__(256) void prep_kernel(
    const float* __restrict__ x,
    unsigned short* __restrict__ on,
    unsigned short* __restrict__ vT)
{
    __shared__ unsigned short vt[32 * 128];   // [key-row][d], raw gelu bf16
    const int blk = blockIdx.x;               // 512 blocks
    const int batch = blk >> 8;
    const int kb32 = (blk & 255) << 5;
    const int t = threadIdx.x;
    const int r = t >> 3;
    const int d0 = (t & 7) << 4;

    const size_t rowbase = ((size_t)batch * T_DIM + kb32 + r) * D_DIM;
    float g[16];
    #pragma unroll
    for (int i = 0; i < 16; i += 4) {
        f32x4 xv = *reinterpret_cast<const f32x4*>(x + rowbase + d0 + i);
        g[i+0] = gelu_tanh(xv[0]); g[i+1] = gelu_tanh(xv[1]);
        g[i+2] = gelu_tanh(xv[2]); g[i+3] = gelu_tanh(xv[3]);
    }
    float ss = 0.f;
    #pragma unroll
    for (int i = 0; i < 16; ++i) ss += g[i] * g[i];
    ss += __shfl_xor(ss, 1, 64); ss += __shfl_xor(ss, 2, 64); ss += __shfl_xor(ss, 4, 64);
    const float inv = 1.0f / fmaxf(sqrtf(ss), 1e-6f);

    unsigned pk[8], vp[8];
    #pragma unroll
    for (int i = 0; i < 8; ++i) {
        pk[i] = (unsigned)f2bf(g[2*i] * inv) | ((unsigned)f2bf(g[2*i+1] * inv) << 16);
        vp[i] = (unsigned)f2bf(g[2*i])       | ((unsigned)f2bf(g[2*i+1]) << 16);
    }
    uint4 oa = {pk[0],pk[1],pk[2],pk[3]}, ob = {pk[4],pk[5],pk[6],pk[7]};
    *reinterpret_cast<uint4*>(on + rowbase + d0)     = oa;
    *reinterpret_cast<uint4*>(on + rowbase + d0 + 8) = ob;
    uint4 va = {vp[0],vp[1],vp[2],vp[3]}, vb = {vp[4],vp[5],vp[6],vp[7]};
    *reinterpret_cast<uint4*>(&vt[r * 128 + d0])     = va;
    *reinterpret_cast<uint4*>(&vt[r * 128 + d0 + 8]) = vb;

    __syncthreads();

    // write vT'[d][kb32 + pos], pos p holds key sigma(p) (swap bits 2,3)
    const int dd = t >> 1, h = (t & 1) * 16;
    unsigned short vals[16];
    #pragma unroll
    for (int j = 0; j < 16; ++j) {
        const int sj = (j & 3) | ((j & 4) << 1) | ((j & 8) >> 1);
        vals[j] = vt[(h + sj) * 128 + dd];
    }
    unsigned wp[8];
    #pragma unroll
    for (int i = 0; i < 8; ++i)
        wp[i] = (unsigned)vals[2*i] | ((unsigned)vals[2*i+1] << 16);
    uint4 wa = {wp[0],wp[1],wp[2],wp[3]}, wb = {wp[4],wp[5],wp[6],wp[7]};
    unsigned short* dst = vT + (size_t)batch * D_DIM * T_DIM + (size_t)dd * T_DIM + kb32 + h;
    *reinterpret_cast<uint4*>(dst)     = wa;
    *reinterpret_cast<uint4*>(dst + 8) = wb;
}

// ---------------------------------------------------------------------------
// attn: block = 128 q-rows (4 INDEPENDENT waves x 32), 32x32x16 MFMA.
// No LDS staging, no barriers: K and V fragments are 16B loads straight from
// L2 (KV working set = 16 MB, fully L2-resident). Softmax in registers with
// fixed max = 0 (|logit| <= 0.49 structurally). Q pre-scaled by
// beta/sqrt(D)*log2e so p = v_exp_f32(s) directly. Each wave loops only its
// own causal key-range.
// ---------------------------------------------------------------------------
__global__ __launch_bounds__(256, 2) void attn_kernel(
    const float* __restrict__ x,
    const unsigned short* __restrict__ on,
    const unsigned short* __restrict__ vT,
    const float* __restrict__ lbr,
    const float* __restrict__ lar,
    unsigned short* __restrict__ partO,
    float* __restrict__ partL,
    float* __restrict__ out,
    int MS)
{
    __shared__ float lbuf[4][32];

    const int bx = blockIdx.x;
    const int batch = bx & 1, tl = bx >> 1;
    const int q0 = 8064 - 128 * tl;            // longest-first
    const int R = q0 + 128;
    int nseg = (R + 511) >> 9; if (nseg > MS) nseg = MS;
    const int seg = blockIdx.y;
    if (seg >= nseg) return;
    const int len = (((R + nseg - 1) / nseg) + 31) & ~31;
    const int s0 = seg * len;
    int s1 = s0 + len; if (s1 > R) s1 = R;

    const int tid = threadIdx.x;
    const int w = tid >> 6, lane = tid & 63;
    const int hi = lane >> 5, cc = lane & 31;
    const int qw0 = q0 + 32 * w;

    // this wave's own causal end (all values are multiples of 32)
    int s1w = qw0 + 32; if (s1w > s1) s1w = s1;
    const int nitw = (s1w > s0) ? ((s1w - s0) >> 5) : 0;

    const float beta = fminf(softplus_f(lbr[0]), 5.0f) + 0.5f;
    const float sc2 = beta * 0.08838834764831843f * 1.4426950408889634f; // beta/sqrt(128)*log2e

    const unsigned short* onb = on + (size_t)batch * T_DIM * D_DIM;
    const unsigned short* vTb = vT + (size_t)batch * D_DIM * T_DIM;

    // Q B-fragments, pre-scaled: B[k=hi*8+j][col=cc] = sc2 * on[qw0+cc][dc*16+hi*8+j]
    bf16x8 qf[8];
    #pragma unroll
    for (int dc = 0; dc < 8; ++dc) {
        bf16x8 q = *reinterpret_cast<const bf16x8*>(
            onb + (size_t)(qw0 + cc) * D_DIM + dc * 16 + hi * 8);
        #pragma unroll
        for (int j = 0; j < 8; ++j) q[j] = (__bf16)((float)q[j] * sc2);
        qf[dc] = q;
    }

    f32x16 acc[4];
    #pragma unroll
    for (int dt = 0; dt < 4; ++dt)
        #pragma unroll
        for (int ri = 0; ri < 16; ++ri) acc[dt][ri] = 0.f;
    float lsum = 0.f;

    for (int it = 0; it < nitw; ++it) {
        const int kb = s0 + (it << 5);
        // ---- QK^T swapped: A=K (direct), B=Q -> s[ri]=S[key=kb+(ri&3)+8(ri>>2)+4hi][q=qw0+cc]
        const unsigned short* kbase = onb + (size_t)(kb + cc) * D_DIM + hi * 8;
        f32x16 s;
        #pragma unroll
        for (int ri = 0; ri < 16; ++ri) s[ri] = 0.f;
        #pragma unroll
        for (int dc = 0; dc < 8; ++dc) {
            bf16x8 kf = *reinterpret_cast<const bf16x8*>(kbase + dc * 16);
            s = __builtin_amdgcn_mfma_f32_32x32x16_bf16(kf, qf[dc], s, 0, 0, 0);
        }
        // ---- softmax, fixed max=0; pack P into A-frags in natural reg order
        bf16x8 pa0, pa1;
        if (kb + 31 <= qw0) {          // fully-valid tile
            #pragma unroll
            for (int ri = 0; ri < 16; ++ri) {
                float p = exp2_fast(s[ri]);
                lsum += p;
                if (ri < 8) pa0[ri] = (__bf16)p; else pa1[ri - 8] = (__bf16)p;
            }
        } else {                        // boundary tile: causal mask
            const int q = qw0 + cc;
            #pragma unroll
            for (int ri = 0; ri < 16; ++ri) {
                const int key = kb + (ri & 3) + 8 * (ri >> 2) + 4 * hi;
                float p = exp2_fast(s[ri]);
                p = (key <= q) ? p : 0.f;
                lsum += p;
                if (ri < 8) pa0[ri] = (__bf16)p; else pa1[ri - 8] = (__bf16)p;
            }
        }
        // ---- PV: A = P (regs), B = V' direct 16B loads (sigma-permuted layout)
        const unsigned short* vbase = vTb + kb + hi * 8;
        #pragma unroll
        for (int dt = 0; dt < 4; ++dt) {
            const size_t rowoff = (size_t)(dt * 32 + cc) * T_DIM;
            bf16x8 vf0 = *reinterpret_cast<const bf16x8*>(vbase + rowoff);
            bf16x8 vf1 = *reinterpret_cast<const bf16x8*>(vbase + rowoff + 16);
            acc[dt] = __builtin_amdgcn_mfma_f32_32x32x16_bf16(pa0, vf0, acc[dt], 0, 0, 0);
            acc[dt] = __builtin_amdgcn_mfma_f32_32x32x16_bf16(pa1, vf1, acc[dt], 0, 0, 0);
        }
    }

    // L per q-column: sum the two key-halves (hi)
    lsum += __shfl_xor(lsum, 32, 64);

    const int tile_lin = tl * 2 + batch;
    if (nseg > 1) {
        const size_t slot = (size_t)tile_lin * MS + seg;
        unsigned short* po = partO + slot * (128 * 128);
        #pragma unroll
        for (int ri = 0; ri < 16; ++ri) {
            const int qr = (ri & 3) + 8 * (ri >> 2) + 4 * hi;
            #pragma unroll
            for (int dt = 0; dt < 4; ++dt)
                po[(32 * w + qr) * 128 + dt * 32 + cc] = f2bf(acc[dt][ri]);
        }
        if (lane < 32) partL[slot * 128 + 32 * w + cc] = lsum;
    } else {
        // direct epilogue; per-wave LDS bounce to redistribute L (no barrier:
        // same-wave write->read, compiler inserts lgkmcnt)
        if (lane < 32) lbuf[w][cc] = lsum;
        const float alpha = softplus_f(lar[0]);
        #pragma unroll
        for (int ri = 0; ri < 16; ++ri) {
            const int qr = (ri & 3) + 8 * (ri >> 2) + 4 * hi;
            const float invL = 1.0f / lbuf[w][qr];
            #pragma unroll
            for (int dt = 0; dt < 4; ++dt) {
                const float mu = acc[dt][ri] * invL;
                const size_t gi = ((size_t)batch * T_DIM + q0 + 32 * w + qr) * D_DIM + dt * 32 + cc;
                const float gv = gelu_tanh(x[gi]);
                out[gi] = gv + alpha * (gv - mu);
            }
        }
    }
}

// ---------------------------------------------------------------------------
// reduce: sum bf16 partials (plain add across segments) + epilogue
// ---------------------------------------------------------------------------
__global__ __launch_bounds__(256) void reduce_kernel(
    const float* __restrict__ x,
    const float* __restrict__ lar,
    const unsigned short* __restrict__ partO,
    const float* __restrict__ partL,
    float* __restrict__ out,
    int MS)
{
    const int idx = blockIdx.x * 256 + threadIdx.x;  // 524288 threads
    const int row = idx >> 5;
    const int d0 = (idx & 31) << 2;
    const int batch = row >> 13, q = row & 8191;
    const int tl = 63 - (q >> 7);
    const int R = 8192 - 128 * tl;
    int nseg = (R + 511) >> 9; if (nseg > MS) nseg = MS;
    if (nseg <= 1) return;                           // written directly by attn
    const int roff = q & 127;
    const int tile_lin = tl * 2 + batch;

    float o0 = 0.f, o1 = 0.f, o2 = 0.f, o3 = 0.f, L = 0.f;
    for (int s = 0; s < nseg; ++s) {
        const size_t slot = (size_t)tile_lin * MS + s;
        const unsigned short* po = partO + slot * (128 * 128) + roff * 128 + d0;
        o0 += bf2f(po[0]); o1 += bf2f(po[1]); o2 += bf2f(po[2]); o3 += bf2f(po[3]);
        L += partL[slot * 128 + roff];
    }
    const float invL = 1.0f / L;
    const float alpha = softplus_f(lar[0]);
    const size_t gi = (size_t)row * D_DIM + d0;
    const f32x4 xv = *reinterpret_cast<const f32x4*>(x + gi);
    f32x4 ov;
    const float mu[4] = {o0 * invL, o1 * invL, o2 * invL, o3 * invL};
    #pragma unroll
    for (int j = 0; j < 4; ++j) {
        const float gv = gelu_tanh(xv[j]);
        ov[j] = gv + alpha * (gv - mu[j]);
    }
    *reinterpret_cast<f32x4*>(out + gi) = ov;
}

extern "C" void kernel_launch(void* const* d_in, const int* in_sizes, int n_in,
                              void* d_out, int out_size, void* d_ws, size_t ws_size,
                              hipStream_t stream) {
    const float* x = (const float*)d_in[0];
    const float* lbr = (const float*)d_in[1];
    const float* lar = (const float*)d_in[2];
    float* out = (float*)d_out;

    unsigned short* on = (unsigned short*)d_ws;              // 4 MiB
    unsigned short* vT = on + (size_t)2 * T_DIM * D_DIM;     // 4 MiB
    const size_t fixed = (size_t)8 * 1024 * 1024;

    int MS = 1;
    if (ws_size > fixed + (1 << 20)) {
        const long long per = 128ll * (128 * 128 * 2 + 128 * 4); // partO + partL per seg level
        long long avail = (long long)ws_size - (long long)fixed - (1 << 20);
        MS = (int)(avail / per);
        if (MS > 16) MS = 16;
        if (MS < 1) MS = 1;
    }
    unsigned short* partO = (unsigned short*)((char*)d_ws + fixed);
    float* partL = (float*)((char*)partO + (size_t)128 * MS * 128 * 128 * 2);

    prep_kernel<<<dim3(512), dim3(256), 0, stream>>>(x, on, vT);
    attn_kernel<<<dim3(128, MS), dim3(256), 0, stream>>>(x, on, vT, lbr, lar,
                                                         partO, partL, out, MS);
    if (MS > 1)
        reduce_kernel<<<dim3(2048), dim3(256), 0, stream>>>(x, lar, partO, partL, out, MS);
}

// Round 6
// 99.661 us; speedup vs baseline: 1.9601x; 1.9601x over previous
//
#include <hip/hip_runtime.h>
#include <hip/hip_bf16.h>
#include <math.h>

#define T_DIM 8192
#define D_DIM 128

typedef __attribute__((ext_vector_type(8))) __bf16 bf16x8;
typedef __attribute__((ext_vector_type(16))) float f32x16;
typedef __attribute__((ext_vector_type(4))) float f32x4;

static __device__ __forceinline__ unsigned short f2bf(float f) {
    unsigned u = __builtin_bit_cast(unsigned, f);
    unsigned r = (u + 0x7FFFu + ((u >> 16) & 1u)) >> 16;
    return (unsigned short)r;
}
static __device__ __forceinline__ float bf2f(unsigned short h) {
    unsigned u = ((unsigned)h) << 16;
    return __builtin_bit_cast(float, u);
}
static __device__ __forceinline__ float exp2_fast(float x) {
    float r;
    asm("v_exp_f32 %0, %1" : "=v"(r) : "v"(x));
    return r;
}
static __device__ __forceinline__ float gelu_tanh(float x) {
    const float c = 0.7978845608028654f; // sqrt(2/pi)
    float u = c * (x + 0.044715f * x * x * x);
    float e = __expf(2.0f * u);
    float th = 1.0f - 2.0f / (e + 1.0f);
    return 0.5f * x * (1.0f + th);
}
static __device__ __forceinline__ float softplus_f(float x) {
    return (x > 20.0f) ? x : log1pf(__expf(x));
}
// async global->LDS DMA, 16B per lane, dest = wave-uniform base + lane*16
static __device__ __forceinline__ void gload16(const unsigned short* g, unsigned short* l) {
    __builtin_amdgcn_global_load_lds(
        (const __attribute__((address_space(1))) void*)g,
        (__attribute__((address_space(3))) void*)l, 16, 0, 0);
}

// ---------------------------------------------------------------------------
// prep: gelu, row-normalize -> on (row-major bf16); raw gelu -> vT' transposed
// with per-32-block column permutation sigma(k) = swap bits 2<->3 (involution).
// ---------------------------------------------------------------------------
__global__ __launch_bounds__(256) void prep_kernel(
    const float* __restrict__ x,
    unsigned short* __restrict__ on,
    unsigned short* __restrict__ vT)
{
    __shared__ unsigned short vt[32 * 128];   // [key-row][d], raw gelu bf16
    const int blk = blockIdx.x;               // 512 blocks
    const int batch = blk >> 8;
    const int kb32 = (blk & 255) << 5;
    const int t = threadIdx.x;
    const int r = t >> 3;
    const int d0 = (t & 7) << 4;

    const size_t rowbase = ((size_t)batch * T_DIM + kb32 + r) * D_DIM;
    float g[16];
    #pragma unroll
    for (int i = 0; i < 16; i += 4) {
        f32x4 xv = *reinterpret_cast<const f32x4*>(x + rowbase + d0 + i);
        g[i+0] = gelu_tanh(xv[0]); g[i+1] = gelu_tanh(xv[1]);
        g[i+2] = gelu_tanh(xv[2]); g[i+3] = gelu_tanh(xv[3]);
    }
    float ss = 0.f;
    #pragma unroll
    for (int i = 0; i < 16; ++i) ss += g[i] * g[i];
    ss += __shfl_xor(ss, 1, 64); ss += __shfl_xor(ss, 2, 64); ss += __shfl_xor(ss, 4, 64);
    const float inv = 1.0f / fmaxf(sqrtf(ss), 1e-6f);

    unsigned pk[8], vp[8];
    #pragma unroll
    for (int i = 0; i < 8; ++i) {
        pk[i] = (unsigned)f2bf(g[2*i] * inv) | ((unsigned)f2bf(g[2*i+1] * inv) << 16);
        vp[i] = (unsigned)f2bf(g[2*i])       | ((unsigned)f2bf(g[2*i+1]) << 16);
    }
    uint4 oa = {pk[0],pk[1],pk[2],pk[3]}, ob = {pk[4],pk[5],pk[6],pk[7]};
    *reinterpret_cast<uint4*>(on + rowbase + d0)     = oa;
    *reinterpret_cast<uint4*>(on + rowbase + d0 + 8) = ob;
    uint4 va = {vp[0],vp[1],vp[2],vp[3]}, vb = {vp[4],vp[5],vp[6],vp[7]};
    *reinterpret_cast<uint4*>(&vt[r * 128 + d0])     = va;
    *reinterpret_cast<uint4*>(&vt[r * 128 + d0 + 8]) = vb;

    __syncthreads();

    // write vT'[d][kb32 + pos], pos p holds key sigma(p) (swap bits 2,3)
    const int dd = t >> 1, h = (t & 1) * 16;
    unsigned short vals[16];
    #pragma unroll
    for (int j = 0; j < 16; ++j) {
        const int sj = (j & 3) | ((j & 4) << 1) | ((j & 8) >> 1);
        vals[j] = vt[(h + sj) * 128 + dd];
    }
    unsigned wp[8];
    #pragma unroll
    for (int i = 0; i < 8; ++i)
        wp[i] = (unsigned)vals[2*i] | ((unsigned)vals[2*i+1] << 16);
    uint4 wa = {wp[0],wp[1],wp[2],wp[3]}, wb = {wp[4],wp[5],wp[6],wp[7]};
    unsigned short* dst = vT + (size_t)batch * D_DIM * T_DIM + (size_t)dd * T_DIM + kb32 + h;
    *reinterpret_cast<uint4*>(dst)     = wa;
    *reinterpret_cast<uint4*>(dst + 8) = wb;
}

// ---------------------------------------------------------------------------
// attn: block = 256 q-rows (4 waves x 64: two 32-col MFMA groups per wave).
// 32x32x16 MFMA, K/V double-buffered in LDS via global_load_lds (pre-swizzled
// source, linear dest), counted-vmcnt pipeline (loads in flight across
// barriers), softmax in registers with fixed max = 0 (|logit| <= 0.49
// structurally), P -> PV A-frag = QK accumulator in natural register order
// (V columns pre-permuted by sigma).
// ---------------------------------------------------------------------------
__global__ __launch_bounds__(256, 2) void attn_kernel(
    const float* __restrict__ x,
    const unsigned short* __restrict__ on,
    const unsigned short* __restrict__ vT,
    const float* __restrict__ lbr,
    const float* __restrict__ lar,
    unsigned short* __restrict__ partO,
    float* __restrict__ partL,
    float* __restrict__ out,
    int MS)
{
    __shared__ unsigned short ks[2][32 * 128]; // K tile [key][d], chunk-swizzled
    __shared__ unsigned short vs[2][128 * 32]; // V tile [d][slot], chunk-swizzled
    __shared__ float lbuf[4][64];

    const int bx = blockIdx.x;
    const int batch = bx & 1, tl = bx >> 1;    // 32 tiles per batch
    const int q0 = 7936 - 256 * tl;            // longest-first
    const int R = q0 + 256;
    int nseg = (R + 511) >> 9; if (nseg > MS) nseg = MS;
    const int seg = blockIdx.y;
    if (seg >= nseg) return;
    const int len = (((R + nseg - 1) / nseg) + 31) & ~31;
    const int s0 = seg * len;
    int s1 = s0 + len; if (s1 > R) s1 = R;
    const int nit = (s1 - s0) >> 5;

    const int tid = threadIdx.x;
    const int w = tid >> 6, lane = tid & 63;
    const int hi = lane >> 5, cc = lane & 31;
    const int qw0 = q0 + 64 * w;               // wave's first q row (owns 64)

    const float beta = fminf(softplus_f(lbr[0]), 5.0f) + 0.5f;
    const float sc2 = beta * 0.08838834764831843f * 1.4426950408889634f;

    const unsigned short* onb = on + (size_t)batch * T_DIM * D_DIM;
    const unsigned short* vTb = vT + (size_t)batch * D_DIM * T_DIM;

    // Q B-fragments for both 32-col groups, pre-scaled by beta/sqrt(D)*log2e
    bf16x8 qf0[8], qf1[8];
    #pragma unroll
    for (int dc = 0; dc < 8; ++dc) {
        bf16x8 q0v = *reinterpret_cast<const bf16x8*>(
            onb + (size_t)(qw0 + cc) * D_DIM + dc * 16 + hi * 8);
        bf16x8 q1v = *reinterpret_cast<const bf16x8*>(
            onb + (size_t)(qw0 + 32 + cc) * D_DIM + dc * 16 + hi * 8);
        #pragma unroll
        for (int j = 0; j < 8; ++j) {
            q0v[j] = (__bf16)((float)q0v[j] * sc2);
            q1v[j] = (__bf16)((float)q1v[j] * sc2);
        }
        qf0[dc] = q0v; qf1[dc] = q1v;
    }

    f32x16 a0[4], a1[4];
    #pragma unroll
    for (int dt = 0; dt < 4; ++dt)
        #pragma unroll
        for (int ri = 0; ri < 16; ++ri) { a0[dt][ri] = 0.f; a1[dt][ri] = 0.f; }
    float lsum0 = 0.f, lsum1 = 0.f;

    // read-side constants
    const int vswz = hi ^ ((cc >> 1) & 3);
    const int kd0 = w * 1024;                  // u16 LDS base per wave (both arrays)

    // staging source addresses (per-lane, swizzle baked into source)
    const int krow0 = w * 8 + (lane >> 4);
    const int krow1 = krow0 + 4;
    const unsigned short* kS0 = onb + krow0 * D_DIM + (((lane & 15) ^ (krow0 & 7)) * 8);
    const unsigned short* kS1 = onb + krow1 * D_DIM + (((lane & 15) ^ (krow1 & 7)) * 8);
    const int vd0 = w * 32 + (lane >> 2);
    const int vp0 = (lane & 3) ^ ((vd0 >> 1) & 3);   // same for vd0+16
    const unsigned short* vS0 = vTb + (size_t)vd0 * T_DIM + vp0 * 8;
    const unsigned short* vS1 = vTb + (size_t)(vd0 + 16) * T_DIM + vp0 * 8;

#define STAGE(B, KB) do { \
    gload16(kS0 + (size_t)(KB) * D_DIM, &ks[B][kd0]); \
    gload16(kS1 + (size_t)(KB) * D_DIM, &ks[B][kd0 + 512]); \
    gload16(vS0 + (KB), &vs[B][kd0]); \
    gload16(vS1 + (KB), &vs[B][kd0 + 512]); \
} while (0)

    STAGE(0, s0);
    if (nit > 1) STAGE(1, s0 + 32);

    for (int it = 0; it < nit; ++it) {
        const int kb = s0 + (it << 5);
        const int b = it & 1;
        if (it + 1 < nit) asm volatile("s_waitcnt vmcnt(4)" ::: "memory");
        else              asm volatile("s_waitcnt vmcnt(0)" ::: "memory");
        __builtin_amdgcn_s_barrier();
        asm volatile("" ::: "memory");

        if (kb <= qw0 + 63) {                  // wave-uniform causal skip
            const unsigned short* ksb = &ks[b][0];
            const unsigned short* vsb = &vs[b][0];
            // QK^T swapped (A=K, B=Q), both cols share each K fragment
            f32x16 s0v, s1v;
            #pragma unroll
            for (int ri = 0; ri < 16; ++ri) { s0v[ri] = 0.f; s1v[ri] = 0.f; }
            __builtin_amdgcn_s_setprio(1);
            #pragma unroll
            for (int dc = 0; dc < 8; ++dc) {
                bf16x8 kf = *reinterpret_cast<const bf16x8*>(
                    ksb + cc * 128 + (((dc * 2 + hi) ^ (cc & 7)) * 8));
                s0v = __builtin_amdgcn_mfma_f32_32x32x16_bf16(kf, qf0[dc], s0v, 0, 0, 0);
                s1v = __builtin_amdgcn_mfma_f32_32x32x16_bf16(kf, qf1[dc], s1v, 0, 0, 0);
            }
            __builtin_amdgcn_s_setprio(0);
            // softmax col0 (rows qw0..qw0+31), fixed max = 0
            bf16x8 p00, p01, p10, p11;
            if (kb + 31 <= qw0) {
                #pragma unroll
                for (int ri = 0; ri < 16; ++ri) {
                    float p = exp2_fast(s0v[ri]); lsum0 += p;
                    if (ri < 8) p00[ri] = (__bf16)p; else p01[ri - 8] = (__bf16)p;
                }
            } else {
                const int q = qw0 + cc;
                #pragma unroll
                for (int ri = 0; ri < 16; ++ri) {
                    const int key = kb + (ri & 3) + 8 * (ri >> 2) + 4 * hi;
                    float p = exp2_fast(s0v[ri]);
                    p = (key <= q) ? p : 0.f; lsum0 += p;
                    if (ri < 8) p00[ri] = (__bf16)p; else p01[ri - 8] = (__bf16)p;
                }
            }
            // softmax col1 (rows qw0+32..qw0+63)
            if (kb + 31 <= qw0 + 32) {
                #pragma unroll
                for (int ri = 0; ri < 16; ++ri) {
                    float p = exp2_fast(s1v[ri]); lsum1 += p;
                    if (ri < 8) p10[ri] = (__bf16)p; else p11[ri - 8] = (__bf16)p;
                }
            } else {
                const int q = qw0 + 32 + cc;
                #pragma unroll
                for (int ri = 0; ri < 16; ++ri) {
                    const int key = kb + (ri & 3) + 8 * (ri >> 2) + 4 * hi;
                    float p = exp2_fast(s1v[ri]);
                    p = (key <= q) ? p : 0.f; lsum1 += p;
                    if (ri < 8) p10[ri] = (__bf16)p; else p11[ri - 8] = (__bf16)p;
                }
            }
            // PV: V fragments shared by both cols
            __builtin_amdgcn_s_setprio(1);
            #pragma unroll
            for (int dt = 0; dt < 4; ++dt) {
                const int rb = (dt * 32 + cc) * 32;
                bf16x8 vf0 = *reinterpret_cast<const bf16x8*>(vsb + rb + (vswz * 8));
                bf16x8 vf1 = *reinterpret_cast<const bf16x8*>(vsb + rb + ((2 ^ vswz) * 8));
                a0[dt] = __builtin_amdgcn_mfma_f32_32x32x16_bf16(p00, vf0, a0[dt], 0, 0, 0);
                a0[dt] = __builtin_amdgcn_mfma_f32_32x32x16_bf16(p01, vf1, a0[dt], 0, 0, 0);
                a1[dt] = __builtin_amdgcn_mfma_f32_32x32x16_bf16(p10, vf0, a1[dt], 0, 0, 0);
                a1[dt] = __builtin_amdgcn_mfma_f32_32x32x16_bf16(p11, vf1, a1[dt], 0, 0, 0);
            }
            __builtin_amdgcn_s_setprio(0);
        }
        __builtin_amdgcn_s_barrier();
        asm volatile("" ::: "memory");
        if (it + 2 < nit) STAGE(b, kb + 64);
    }
#undef STAGE

    // column sums: combine the two key-halves (hi)
    lsum0 += __shfl_xor(lsum0, 32, 64);
    lsum1 += __shfl_xor(lsum1, 32, 64);

    const int tile_lin = tl * 2 + batch;
    if (nseg > 1) {
        const size_t slot = (size_t)tile_lin * MS + seg;
        unsigned short* po = partO + slot * (256 * 128);
        #pragma unroll
        for (int ri = 0; ri < 16; ++ri) {
            const int qr = (ri & 3) + 8 * (ri >> 2) + 4 * hi;
            #pragma unroll
            for (int dt = 0; dt < 4; ++dt) {
                po[(64 * w + qr) * 128 + dt * 32 + cc]      = f2bf(a0[dt][ri]);
                po[(64 * w + 32 + qr) * 128 + dt * 32 + cc] = f2bf(a1[dt][ri]);
            }
        }
        if (lane < 32) {
            partL[slot * 256 + 64 * w + cc]      = lsum0;
            partL[slot * 256 + 64 * w + 32 + cc] = lsum1;
        }
    } else {
        if (lane < 32) { lbuf[w][cc] = lsum0; lbuf[w][32 + cc] = lsum1; }
        const float alpha = softplus_f(lar[0]);
        #pragma unroll
        for (int ri = 0; ri < 16; ++ri) {
            const int qr = (ri & 3) + 8 * (ri >> 2) + 4 * hi;
            const float iL0 = 1.0f / lbuf[w][qr];
            const float iL1 = 1.0f / lbuf[w][32 + qr];
            #pragma unroll
            for (int dt = 0; dt < 4; ++dt) {
                {
                    const size_t gi = ((size_t)batch * T_DIM + qw0 + qr) * D_DIM + dt * 32 + cc;
                    const float gv = gelu_tanh(x[gi]);
                    out[gi] = gv + alpha * (gv - a0[dt][ri] * iL0);
                }
                {
                    const size_t gi = ((size_t)batch * T_DIM + qw0 + 32 + qr) * D_DIM + dt * 32 + cc;
                    const float gv = gelu_tanh(x[gi]);
                    out[gi] = gv + alpha * (gv - a1[dt][ri] * iL1);
                }
            }
        }
    }
}

// ---------------------------------------------------------------------------
// reduce: sum bf16 partials (plain add across segments) + epilogue
// ---------------------------------------------------------------------------
__global__ __launch_bounds__(256) void reduce_kernel(
    const float* __restrict__ x,
    const float* __restrict__ lar,
    const unsigned short* __restrict__ partO,
    const float* __restrict__ partL,
    float* __restrict__ out,
    int MS)
{
    const int idx = blockIdx.x * 256 + threadIdx.x;  // 524288 threads
    const int row = idx >> 5;
    const int d0 = (idx & 31) << 2;
    const int batch = row >> 13, q = row & 8191;
    const int tl = 31 - (q >> 8);
    const int R = 8192 - 256 * tl;
    int nseg = (R + 511) >> 9; if (nseg > MS) nseg = MS;
    if (nseg <= 1) return;                           // written directly by attn
    const int roff = q & 255;
    const int tile_lin = tl * 2 + batch;

    float o0 = 0.f, o1 = 0.f, o2 = 0.f, o3 = 0.f, L = 0.f;
    for (int s = 0; s < nseg; ++s) {
        const size_t slot = (size_t)tile_lin * MS + s;
        const unsigned short* po = partO + slot * (256 * 128) + roff * 128 + d0;
        o0 += bf2f(po[0]); o1 += bf2f(po[1]); o2 += bf2f(po[2]); o3 += bf2f(po[3]);
        L += partL[slot * 256 + roff];
    }
    const float invL = 1.0f / L;
    const float alpha = softplus_f(lar[0]);
    const size_t gi = (size_t)row * D_DIM + d0;
    const f32x4 xv = *reinterpret_cast<const f32x4*>(x + gi);
    f32x4 ov;
    const float mu[4] = {o0 * invL, o1 * invL, o2 * invL, o3 * invL};
    #pragma unroll
    for (int j = 0; j < 4; ++j) {
        const float gv = gelu_tanh(xv[j]);
        ov[j] = gv + alpha * (gv - mu[j]);
    }
    *reinterpret_cast<f32x4*>(out + gi) = ov;
}

extern "C" void kernel_launch(void* const* d_in, const int* in_sizes, int n_in,
                              void* d_out, int out_size, void* d_ws, size_t ws_size,
                              hipStream_t stream) {
    const float* x = (const float*)d_in[0];
    const float* lbr = (const float*)d_in[1];
    const float* lar = (const float*)d_in[2];
    float* out = (float*)d_out;

    unsigned short* on = (unsigned short*)d_ws;              // 4 MiB
    unsigned short* vT = on + (size_t)2 * T_DIM * D_DIM;     // 4 MiB
    const size_t fixed = (size_t)8 * 1024 * 1024;

    int MS = 1;
    if (ws_size > fixed + (1 << 20)) {
        const long long per = 64ll * (256 * 128 * 2 + 256 * 4); // partO + partL per seg level
        long long avail = (long long)ws_size - (long long)fixed - (1 << 20);
        MS = (int)(avail / per);
        if (MS > 16) MS = 16;
        if (MS < 1) MS = 1;
    }
    unsigned short* partO = (unsigned short*)((char*)d_ws + fixed);
    float* partL = (float*)(partO + (size_t)64 * MS * 256 * 128);

    prep_kernel<<<dim3(512), dim3(256), 0, stream>>>(x, on, vT);
    attn_kernel<<<dim3(64, MS), dim3(256), 0, stream>>>(x, on, vT, lbr, lar,
                                                        partO, partL, out, MS);
    if (MS > 1)
        reduce_kernel<<<dim3(2048), dim3(256), 0, stream>>>(x, lar, partO, partL, out, MS);
}